// Round 1
// baseline (5741.983 us; speedup 1.0000x reference)
//
#include <hip/hip_runtime.h>

// LSTM static RNN: B=128, T=512, D=512, H=512, gates i,j,f,o, FORGET_BIAS=1.0
// Round 1: correctness-first multi-launch baseline.
//   - W packed once per launch into bf16 MFMA-B-fragment layout (4 MB in ws)
//   - 512 per-step kernels (graph nodes), grid 256 wgs x 256 thr
//     wg = [16 batch rows] x [16 n-values]; wave g computes gate g's 16x16 tile
//   - K=1024 fused (x part k<512 from fp32 word_vectors w/ on-the-fly cvt,
//     h part k>=512 from bf16 double-buffered h)
//   - c / h state fp32 (bf16 only on matmul inputs), fp32 accumulate via MFMA

#define B_ 128
#define T_ 512
#define D_ 512
#define H_ 512

typedef __bf16 bf16x8 __attribute__((ext_vector_type(8)));
typedef float f32x4 __attribute__((ext_vector_type(4)));

static __device__ __forceinline__ unsigned short f2bf(float f) {
  return __builtin_bit_cast(unsigned short, (__bf16)f);
}

// ---- pack W [1024][2048] fp32 -> bf16 B-fragment layout ----
// frag id f = ntile*32 + ktile (ntile = n>>4, ktile = k>>5)
// within frag: lane = (n&15) | (((k>>3)&3)<<4), j = k&7
// Wp[(f*64 + lane)*8 + j] = bf16(W[k][n])   -> per-wave B-frag load is one
// coalesced 16B/lane read.
__global__ __launch_bounds__(256) void pack_w_kernel(const float* __restrict__ W,
                                                     unsigned short* __restrict__ Wp) {
  int tid = blockIdx.x * 256 + threadIdx.x;  // tid = k*2048 + n, coalesced read
  int n = tid & 2047;
  int k = tid >> 11;
  int ntile = n >> 4;
  int ktile = k >> 5;
  int lane = (n & 15) | (((k >> 3) & 3) << 4);
  int j = k & 7;
  int f = ntile * 32 + ktile;
  Wp[((f << 6) + lane) * 8 + j] = f2bf(W[tid]);
}

__global__ __launch_bounds__(256) void init_state_kernel(
    const float* __restrict__ ic, const float* __restrict__ ih,
    float* __restrict__ c, float* __restrict__ h32, unsigned short* __restrict__ hb) {
  int i = blockIdx.x * 256 + threadIdx.x;
  c[i] = ic[i];
  float h = ih[i];
  h32[i] = h;
  hb[i] = f2bf(h);
}

// ---- one timestep ----
// grid 256: bg = blockIdx&7 (16 batch rows), ng = blockIdx>>3 (16 n-values)
// wave g (threadIdx>>6) computes z tile [16b x 16n] for gate g (cols g*512+n0..+16)
__global__ __launch_bounds__(256) void lstm_step_kernel(
    const float* __restrict__ wv, const int* __restrict__ nw,
    const unsigned short* __restrict__ Wp, const float* __restrict__ bias,
    const unsigned short* __restrict__ hin, unsigned short* __restrict__ hout,
    float* __restrict__ cbuf, float* __restrict__ h32,
    float* __restrict__ out, int t) {
  __shared__ float zbuf[4][16][16];

  const int lane = threadIdx.x & 63;
  const int g = threadIdx.x >> 6;
  const int bg = blockIdx.x & 7;
  const int ng = blockIdx.x >> 3;
  const int m0 = bg << 4;
  const int n0 = ng << 4;
  const int col0 = (g << 9) + n0;
  const int arow = m0 + (lane & 15);   // A-frag: batch row for this lane
  const int kq = (lane >> 4) << 3;     // A/B-frag: k sub-offset (0,8,16,24)

  f32x4 acc = {0.f, 0.f, 0.f, 0.f};
  const int ntile = col0 >> 4;
  const uint4* wp = ((const uint4*)Wp) + ((size_t)(ntile * 32) << 6) + lane;
  const float* xrow = wv + ((size_t)arow * T_ + t) * D_;

  // x part: k in [0,512), W rows 0..511
#pragma unroll 8
  for (int kt = 0; kt < 16; ++kt) {
    int k = (kt << 5) + kq;
    float4 xa = *(const float4*)(xrow + k);
    float4 xb = *(const float4*)(xrow + k + 4);
    bf16x8 a;
    a[0] = (__bf16)xa.x; a[1] = (__bf16)xa.y; a[2] = (__bf16)xa.z; a[3] = (__bf16)xa.w;
    a[4] = (__bf16)xb.x; a[5] = (__bf16)xb.y; a[6] = (__bf16)xb.z; a[7] = (__bf16)xb.w;
    uint4 wraw = wp[(size_t)kt << 6];
    bf16x8 b = __builtin_bit_cast(bf16x8, wraw);
    acc = __builtin_amdgcn_mfma_f32_16x16x32_bf16(a, b, acc, 0, 0, 0);
  }
  // h part: k in [512,1024), W rows 512..1023
  const unsigned short* hrow = hin + arow * H_;
#pragma unroll 8
  for (int kt = 16; kt < 32; ++kt) {
    int k = ((kt - 16) << 5) + kq;
    uint4 araw = *(const uint4*)(hrow + k);
    bf16x8 a = __builtin_bit_cast(bf16x8, araw);
    uint4 wraw = wp[(size_t)kt << 6];
    bf16x8 b = __builtin_bit_cast(bf16x8, wraw);
    acc = __builtin_amdgcn_mfma_f32_16x16x32_bf16(a, b, acc, 0, 0, 0);
  }

  // C/D layout (16x16x32): col = lane&15, row = (lane>>4)*4 + reg
  float bv = bias[col0 + (lane & 15)];
  int mq = (lane >> 4) << 2;
  int nl = lane & 15;
  zbuf[g][mq + 0][nl] = acc[0] + bv;
  zbuf[g][mq + 1][nl] = acc[1] + bv;
  zbuf[g][mq + 2][nl] = acc[2] + bv;
  zbuf[g][mq + 3][nl] = acc[3] + bv;
  __syncthreads();

  // elementwise: 256 threads <-> 256 (m,n) cells of this wg's tile
  const int ml = threadIdx.x >> 4;
  const int nl2 = threadIdx.x & 15;
  const int bq = m0 + ml;
  const int n = n0 + nl2;
  float zi = zbuf[0][ml][nl2];
  float zj = zbuf[1][ml][nl2];
  float zf = zbuf[2][ml][nl2];
  float zo = zbuf[3][ml][nl2];
  size_t sidx = ((size_t)bq << 9) + n;
  float cold = cbuf[sidx];
  float hold = h32[sidx];
  float si = 1.f / (1.f + __expf(-zi));
  float sf = 1.f / (1.f + __expf(-(zf + 1.f)));   // FORGET_BIAS = 1.0
  float so = 1.f / (1.f + __expf(-zo));
  float tj = tanhf(zj);
  float nc = cold * sf + si * tj;
  float nh = tanhf(nc) * so;
  bool mask = t < nw[bq];
  float c2 = mask ? nc : cold;
  float h2 = mask ? nh : hold;
  cbuf[sidx] = c2;
  h32[sidx] = h2;
  hout[sidx] = mask ? f2bf(nh) : hin[sidx];
  out[(size_t)t * (B_ * H_) + sidx] = mask ? nh : 0.f;
}

__global__ __launch_bounds__(256) void final_kernel(const float* __restrict__ c,
                                                    const float* __restrict__ h32,
                                                    float* __restrict__ out) {
  int i = blockIdx.x * 256 + threadIdx.x;
  size_t base = (size_t)T_ * B_ * H_;
  out[base + i] = c[i];
  out[base + B_ * H_ + i] = h32[i];
}

extern "C" void kernel_launch(void* const* d_in, const int* in_sizes, int n_in,
                              void* d_out, int out_size, void* d_ws, size_t ws_size,
                              hipStream_t stream) {
  const float* wv = (const float*)d_in[0];       // [B,T,D] fp32
  const int* nw = (const int*)d_in[1];           // [B] int32
  const float* ic = (const float*)d_in[2];       // [B,H]
  const float* ih = (const float*)d_in[3];       // [B,H]
  const float* W = (const float*)d_in[4];        // [D+H, 4H]
  const float* bias = (const float*)d_in[5];     // [4H]
  float* out = (float*)d_out;

  char* ws = (char*)d_ws;
  unsigned short* Wp = (unsigned short*)ws;                 // 4 MB packed bf16 W
  float* cbuf = (float*)(ws + (4u << 20));                  // 256 KB fp32 c
  float* h32 = cbuf + B_ * H_;                              // 256 KB fp32 h
  unsigned short* hb0 = (unsigned short*)(h32 + B_ * H_);   // 128 KB bf16 h ping
  unsigned short* hb1 = hb0 + B_ * H_;                      // 128 KB bf16 h pong

  pack_w_kernel<<<(1024 * 2048) / 256, 256, 0, stream>>>(W, Wp);
  init_state_kernel<<<(B_ * H_) / 256, 256, 0, stream>>>(ic, ih, cbuf, h32, hb0);
  for (int t = 0; t < T_; ++t) {
    const unsigned short* hin = (t & 1) ? hb1 : hb0;
    unsigned short* hout = (t & 1) ? hb0 : hb1;
    lstm_step_kernel<<<256, 256, 0, stream>>>(wv, nw, Wp, bias, hin, hout, cbuf,
                                              h32, out, t);
  }
  final_kernel<<<(B_ * H_) / 256, 256, 0, stream>>>(cbuf, h32, out);
}

// Round 3
// 3193.798 us; speedup vs baseline: 1.7979x; 1.7979x over previous
//
#include <hip/hip_runtime.h>

// Persistent-kernel LSTM: B=128, T=512, D=512, H=512, FORGET_BIAS=1.0
// 128 wgs x 512 thr. wg (mg=wgid&7, hb=wgid>>3): rows 16mg..+16, h-cols
// 32hb..+32, all 4 gates. Wave w: gate g=w&3, col-block jj=w>>2.
// W resident in VGPRs (32 B-frags/wave). c/h state in registers.
//
// R3 sync redesign (R2 diverged under graph replay):
//  - ALL cross-wg data moves via relaxed AGENT-scope atomics (coherence
//    point); no __threadfence, no cache-op reliance.
//  - Barrier = 16 monotonic per-wg epoch flags per row-group. Producer tid0
//    release-stores its flag after __syncthreads (h stores vmcnt-drained);
//    consumer lanes 0..15 acquire-spin one flag each. No counters, no reset.

#define B_ 128
#define T_ 512
#define D_ 512
#define H_ 512

typedef __bf16 bf16x8 __attribute__((ext_vector_type(8)));
typedef float f32x4 __attribute__((ext_vector_type(4)));
typedef unsigned long long u64;

static __device__ __forceinline__ unsigned short f2bf(float f) {
  return __builtin_bit_cast(unsigned short, (__bf16)f);
}

// ---- pack W [1024][2048] fp32 -> bf16 B-frag layout ----
// frag f = (hb*8 + w)*32 + kt;  Wp[(f*64+lane)*8 + j] = bf16(W[k][col])
//   k = kt*32 + (lane>>4)*8 + j,  col = (w&3)*512 + hb*32 + (w>>2)*16 + (lane&15)
__global__ __launch_bounds__(256) void pack_w_kernel(const float* __restrict__ W,
                                                     unsigned short* __restrict__ Wp) {
  int tid = blockIdx.x * 256 + threadIdx.x;  // [0, 2^21)
  int j = tid & 7;
  int lane = (tid >> 3) & 63;
  int f = tid >> 9;
  int kt = f & 31;
  int w = (f >> 5) & 7;
  int hb = f >> 8;
  int k = (kt << 5) + ((lane >> 4) << 3) + j;
  int col = ((w & 3) << 9) + (hb << 5) + ((w >> 2) << 4) + (lane & 15);
  Wp[tid] = f2bf(W[k * 2048 + col]);
}

__global__ void init_bar_kernel(int* __restrict__ bar) {
  bar[blockIdx.x * 256 + threadIdx.x] = 0;
}

__global__ __launch_bounds__(512, 2) void lstm_persistent(
    const float* __restrict__ wv, const int* __restrict__ nw,
    const float* __restrict__ ic, const float* __restrict__ ih,
    const float* __restrict__ bias, const unsigned short* __restrict__ Wp,
    unsigned int* __restrict__ hg, int* __restrict__ bar,
    float* __restrict__ out) {
  __shared__ __align__(16) unsigned short hlds[16 * 512];      // 16 KB
  __shared__ __align__(16) unsigned short xlds[2][16 * 512];   // 32 KB
  __shared__ float zbuf[8][16][16];                            // 8 KB

  const int tid = threadIdx.x;
  const int wgid = blockIdx.x;
  const int mg = wgid & 7;   // row group
  const int hb = wgid >> 3;  // h-col block
  const int w = tid >> 6;    // wave 0..7
  const int lane = tid & 63;
  const int g = w & 3;
  const int jj = w >> 2;

  // elementwise cell: 512 threads <-> 16 rows x 32 h-cols
  const int er = tid >> 5;
  const int ec = tid & 31;
  const int grow = (mg << 4) + er;
  const int gcol = (hb << 5) + ec;

  const int nwv = nw[grow];
  float c_reg = ic[grow * H_ + gcol];
  float h_reg = ih[grow * H_ + gcol];

  // W B-frags in VGPRs: kt 0..15 x-part (rows 0..511), 16..31 h-part
  uint4 wfrag[32];
  {
    const uint4* wp = (const uint4*)Wp + (size_t)((hb * 8 + w) * 32) * 64 + lane;
#pragma unroll
    for (int kt = 0; kt < 32; ++kt) wfrag[kt] = wp[kt * 64];
  }
  const float bv = bias[(g << 9) + (hb << 5) + (jj << 4) + (lane & 15)];

  // epoch flags: one per (mg, hb), 64B apart
  int* myflag = bar + ((mg << 4) + hb) * 16;
  int* gflags = bar + (mg << 4) * 16;  // + i*16 for wg i of this group

  // h cell slot (bf16 index) in group's A-frag-layout buffer; pairs (ec,ec+1)
  // are adjacent -> u32 slot = hslot>>1 for even ec
  const int hslot = (hb << 9) + ((er | ((ec >> 3) << 4)) << 3) + (ec & 7);
  unsigned int* hg0 = hg + mg * 4096;        // parity 0 (u32 view, 16 KB)
  unsigned int* hg1 = hg + (8 + mg) * 4096;  // parity 1

  auto publish_h = [&](unsigned int* dst) {
    unsigned int hv = (unsigned int)f2bf(h_reg);
    unsigned int up = (unsigned int)__shfl_down((int)hv, 1);
    if ((tid & 1) == 0)
      __hip_atomic_store(dst + (hslot >> 1), hv | (up << 16), __ATOMIC_RELAXED,
                         __HIP_MEMORY_SCOPE_AGENT);
  };

  auto stage_h = [&](const unsigned int* src) {
    const u64* s = (const u64*)src;
    u64* d = (u64*)hlds;
#pragma unroll
    for (int sdx = 0; sdx < 4; ++sdx) {
      int idx = tid + (sdx << 9);
      d[idx] = __hip_atomic_load(s + idx, __ATOMIC_RELAXED, __HIP_MEMORY_SCOPE_AGENT);
    }
  };

  auto arrive = [&](int epoch) {
    if (tid == 0)
      __hip_atomic_store(myflag, epoch, __ATOMIC_RELEASE, __HIP_MEMORY_SCOPE_AGENT);
  };
  auto wait = [&](int epoch) {
    if (tid < 16) {
      while (__hip_atomic_load(gflags + tid * 16, __ATOMIC_ACQUIRE,
                               __HIP_MEMORY_SCOPE_AGENT) < epoch)
        __builtin_amdgcn_s_sleep(1);
    }
    __syncthreads();
  };

  auto load_x = [&](int buf, int tt) {  // gather x[.,tt,.] -> A-frag LDS
    if (tt >= T_) return;
#pragma unroll
    for (int s = 0; s < 2; ++s) {
      int e = tid + (s << 9);
      int ktx = e >> 6;
      int le = e & 63;
      int r = le & 15;
      int d = (ktx << 5) + ((le >> 4) << 3);
      const float* src = wv + ((size_t)((mg << 4) + r) * T_ + tt) * D_ + d;
      float4 xa = *(const float4*)src;
      float4 xb = *(const float4*)(src + 4);
      bf16x8 v;
      v[0] = (__bf16)xa.x; v[1] = (__bf16)xa.y; v[2] = (__bf16)xa.z; v[3] = (__bf16)xa.w;
      v[4] = (__bf16)xb.x; v[5] = (__bf16)xb.y; v[6] = (__bf16)xb.z; v[7] = (__bf16)xb.w;
      *(bf16x8*)&xlds[buf][(ktx << 9) + (le << 3)] = v;
    }
  };

  auto xpart = [&](int buf) {
    f32x4 a = {0.f, 0.f, 0.f, 0.f};
#pragma unroll
    for (int kt = 0; kt < 16; ++kt) {
      bf16x8 af = *(const bf16x8*)&xlds[buf][(kt << 9) + (lane << 3)];
      a = __builtin_amdgcn_mfma_f32_16x16x32_bf16(
          af, __builtin_bit_cast(bf16x8, wfrag[kt]), a, 0, 0, 0);
    }
    return a;
  };

  // ---- prologue ----
  load_x(0, 0);
  __syncthreads();
  f32x4 acc = xpart(0);
  load_x(1, 1);
  publish_h(hg0);
  __syncthreads();   // h[0] stores drained (vmcnt) before flag release
  arrive(1);
  wait(1);

  for (int t = 0; t < T_; ++t) {
    const int par = t & 1;
    const unsigned int* hsrc = par ? hg1 : hg0;
    unsigned int* hdst = par ? hg0 : hg1;

    // ---- phase A (critical path): stage h, h-MFMAs, gates, publish ----
    stage_h(hsrc);
    __syncthreads();
#pragma unroll
    for (int kt = 0; kt < 16; ++kt) {
      bf16x8 af = *(const bf16x8*)&hlds[(kt << 9) + (lane << 3)];
      acc = __builtin_amdgcn_mfma_f32_16x16x32_bf16(
          af, __builtin_bit_cast(bf16x8, wfrag[16 + kt]), acc, 0, 0, 0);
    }
    {  // C/D layout: col=lane&15, row=(lane>>4)*4+reg
      int q = lane >> 4, cl = lane & 15;
#pragma unroll
      for (int v = 0; v < 4; ++v) zbuf[w][q * 4 + v][cl] = acc[v] + bv;
    }
    __syncthreads();
    {
      int ej = ec >> 4, ecl = ec & 15;
      float zi = zbuf[ej * 4 + 0][er][ecl];
      float zj = zbuf[ej * 4 + 1][er][ecl];
      float zf = zbuf[ej * 4 + 2][er][ecl];
      float zo = zbuf[ej * 4 + 3][er][ecl];
      float si = 1.f / (1.f + __expf(-zi));
      float sf = 1.f / (1.f + __expf(-(zf + 1.f)));  // FORGET_BIAS
      float so = 1.f / (1.f + __expf(-zo));
      float tj = tanhf(zj);
      float nc = c_reg * sf + si * tj;
      float nh = tanhf(nc) * so;
      bool m = t < nwv;
      c_reg = m ? nc : c_reg;
      h_reg = m ? nh : h_reg;
      out[(size_t)t * (B_ * H_) + grow * H_ + gcol] = m ? nh : 0.f;
      publish_h(hdst);
    }
    __syncthreads();   // h[t+1] stores drained before flag release
    arrive(t + 2);
    // ---- phase B (overlap): x-part of t+1, prefetch x[t+2] ----
    if (t + 1 < T_) {
      acc = xpart(1 - par);   // x[t+1], staged at t-1
      load_x(par, t + 2);     // refill buffer last read at t-1
    }
    wait(t + 2);
  }

  size_t base = (size_t)T_ * (B_ * H_);
  out[base + grow * H_ + gcol] = c_reg;
  out[base + B_ * H_ + grow * H_ + gcol] = h_reg;
}

extern "C" void kernel_launch(void* const* d_in, const int* in_sizes, int n_in,
                              void* d_out, int out_size, void* d_ws, size_t ws_size,
                              hipStream_t stream) {
  const float* wv = (const float*)d_in[0];    // [B,T,D]
  const int* nw = (const int*)d_in[1];        // [B]
  const float* ic = (const float*)d_in[2];    // [B,H]
  const float* ih = (const float*)d_in[3];    // [B,H]
  const float* W = (const float*)d_in[4];     // [D+H, 4H]
  const float* bias = (const float*)d_in[5];  // [4H]
  float* out = (float*)d_out;

  char* ws = (char*)d_ws;
  unsigned short* Wp = (unsigned short*)ws;                // 4 MB packed W
  unsigned int* hg = (unsigned int*)(ws + (4u << 20));     // 256 KB h ping-pong
  int* bar = (int*)(ws + (4u << 20) + (256u << 10));       // 8 KB epoch flags

  init_bar_kernel<<<8, 256, 0, stream>>>(bar);
  pack_w_kernel<<<(1 << 21) / 256, 256, 0, stream>>>(W, Wp);
  lstm_persistent<<<128, 512, 0, stream>>>(wv, nw, ic, ih, bias, Wp, hg, bar, out);
}

// Round 4
// 1753.246 us; speedup vs baseline: 3.2751x; 1.8216x over previous
//
#include <hip/hip_runtime.h>

// Persistent-kernel LSTM: B=128, T=512, D=512, H=512, FORGET_BIAS=1.0
// 128 wgs x 512 thr. wg (mg=wgid&7, hb=wgid>>3): rows 16mg..+16, h-cols
// 32hb..+32, all 4 gates. Wave w: gate g=w&3, col-block jj=w>>2.
// W resident in VGPR/AGPR (32 B-frags/wave). c/h state in registers.
//
// R4: all cross-wg sync RELAXED agent atomics (no buffer_wbl2/buffer_inv on
// the critical path). Ordering: producer __syncthreads drains vmcnt (h sc1
// stores acked at LLC) before tid0's flag store; consumer spin exit is
// control-dependent + asm barrier before sc1 stage loads. Per-wave chunked
// wait+stage: wave w polls producers {2w,2w+1} and stages their 2KB chunks
// (= k-tiles 2w,2w+1 of the h A-frag layout). Fast exp-based tanh/sigmoid.

#define B_ 128
#define T_ 512
#define D_ 512
#define H_ 512

typedef __bf16 bf16x8 __attribute__((ext_vector_type(8)));
typedef float f32x4 __attribute__((ext_vector_type(4)));
typedef unsigned long long u64;

static __device__ __forceinline__ unsigned short f2bf(float f) {
  return __builtin_bit_cast(unsigned short, (__bf16)f);
}
static __device__ __forceinline__ float fast_sigmoid(float x) {
  return __builtin_amdgcn_rcpf(1.f + __expf(-x));
}
static __device__ __forceinline__ float fast_tanh(float x) {
  float xc = fminf(fmaxf(x, -15.f), 15.f);
  float t = __expf(-2.f * xc);
  return (1.f - t) * __builtin_amdgcn_rcpf(1.f + t);
}

// ---- pack W [1024][2048] fp32 -> bf16 B-frag layout ----
// frag f = (hb*8 + w)*32 + kt;  Wp[(f*64+lane)*8 + j] = bf16(W[k][col])
//   k = kt*32 + (lane>>4)*8 + j,  col = (w&3)*512 + hb*32 + (w>>2)*16 + (lane&15)
__global__ __launch_bounds__(256) void pack_w_kernel(const float* __restrict__ W,
                                                     unsigned short* __restrict__ Wp) {
  int tid = blockIdx.x * 256 + threadIdx.x;  // [0, 2^21)
  int j = tid & 7;
  int lane = (tid >> 3) & 63;
  int f = tid >> 9;
  int kt = f & 31;
  int w = (f >> 5) & 7;
  int hb = f >> 8;
  int k = (kt << 5) + ((lane >> 4) << 3) + j;
  int col = ((w & 3) << 9) + (hb << 5) + ((w >> 2) << 4) + (lane & 15);
  Wp[tid] = f2bf(W[k * 2048 + col]);
}

__global__ void init_bar_kernel(int* __restrict__ bar) {
  bar[blockIdx.x * 256 + threadIdx.x] = 0;
}

__global__ __launch_bounds__(512, 2) void lstm_persistent(
    const float* __restrict__ wv, const int* __restrict__ nw,
    const float* __restrict__ ic, const float* __restrict__ ih,
    const float* __restrict__ bias, const unsigned short* __restrict__ Wp,
    unsigned int* __restrict__ hg, int* __restrict__ bar,
    float* __restrict__ out) {
  __shared__ __align__(16) unsigned short hlds[16 * 512];      // 16 KB
  __shared__ __align__(16) unsigned short xlds[2][16 * 512];   // 32 KB
  __shared__ float zbuf[8][16][17];                            // 8.5 KB (padded)

  const int tid = threadIdx.x;
  const int wgid = blockIdx.x;
  const int mg = wgid & 7;   // row group
  const int hb = wgid >> 3;  // h-col block
  const int w = tid >> 6;    // wave 0..7
  const int lane = tid & 63;
  const int g = w & 3;
  const int jj = w >> 2;

  // elementwise cell: 512 threads <-> 16 rows x 32 h-cols
  const int er = tid >> 5;
  const int ec = tid & 31;
  const int grow = (mg << 4) + er;
  const int gcol = (hb << 5) + ec;

  const int nwv = nw[grow];
  float c_reg = ic[grow * H_ + gcol];
  float h_reg = ih[grow * H_ + gcol];

  // W B-frags: kt 0..15 x-part (rows 0..511), 16..31 h-part
  uint4 wfrag[32];
  {
    const uint4* wp = (const uint4*)Wp + (size_t)((hb * 8 + w) * 32) * 64 + lane;
#pragma unroll
    for (int kt = 0; kt < 32; ++kt) wfrag[kt] = wp[kt * 64];
  }
  const float bv = bias[(g << 9) + (hb << 5) + (jj << 4) + (lane & 15)];

  // epoch flags: group mg -> 256 ints; wg hb's flag at stride 16
  int* gflags = bar + (mg << 8);
  int* myflag = gflags + hb * 16;
  int* fq0 = gflags + ((2 * w) << 4);      // wave w polls producers 2w, 2w+1
  int* fq1 = gflags + ((2 * w + 1) << 4);

  // h cell slot (bf16 idx) in group A-frag buffer; producer hb owns
  // u32 range [hb*512, hb*512+512) == k-tile hb of the h A-frag.
  const int hslot = (hb << 9) + ((er | ((ec >> 3) << 4)) << 3) + (ec & 7);
  unsigned int* hg0 = hg + mg * 4096;        // parity 0 (u32 view, 16 KB)
  unsigned int* hg1 = hg + (8 + mg) * 4096;  // parity 1

  auto publish_h = [&](unsigned int* dst) {
    unsigned int hv = (unsigned int)f2bf(h_reg);
    unsigned int up = (unsigned int)__shfl_down((int)hv, 1);
    if ((tid & 1) == 0)
      __hip_atomic_store(dst + (hslot >> 1), hv | (up << 16), __ATOMIC_RELAXED,
                         __HIP_MEMORY_SCOPE_AGENT);
  };

  auto arrive = [&](int epoch) {
    if (tid == 0)
      __hip_atomic_store(myflag, epoch, __ATOMIC_RELAXED, __HIP_MEMORY_SCOPE_AGENT);
  };

  // wait for producers 2w,2w+1 at >= epoch, then stage their 2KB chunks
  auto wait_stage = [&](int epoch, const unsigned int* src) {
    while (true) {
      int a = __hip_atomic_load(fq0, __ATOMIC_RELAXED, __HIP_MEMORY_SCOPE_AGENT);
      int b = __hip_atomic_load(fq1, __ATOMIC_RELAXED, __HIP_MEMORY_SCOPE_AGENT);
      if (a >= epoch && b >= epoch) break;
      __builtin_amdgcn_s_sleep(1);
    }
    __asm__ volatile("" ::: "memory");  // no hoisting stage loads above spin
    const u64* s = (const u64*)src;
    u64* d = (u64*)hlds;
    u64 tmp[8];
#pragma unroll
    for (int q = 0; q < 2; ++q)
#pragma unroll
      for (int i = 0; i < 4; ++i)
        tmp[q * 4 + i] = __hip_atomic_load(s + ((2 * w + q) << 8) + (i << 6) + lane,
                                           __ATOMIC_RELAXED, __HIP_MEMORY_SCOPE_AGENT);
#pragma unroll
    for (int q = 0; q < 2; ++q)
#pragma unroll
      for (int i = 0; i < 4; ++i)
        d[((2 * w + q) << 8) + (i << 6) + lane] = tmp[q * 4 + i];
  };

  auto load_x = [&](int buf, int tt) {  // gather x[.,tt,.] -> A-frag LDS
    if (tt >= T_) return;
#pragma unroll
    for (int s = 0; s < 2; ++s) {
      int e = tid + (s << 9);
      int ktx = e >> 6;
      int le = e & 63;
      int r = le & 15;
      int d = (ktx << 5) + ((le >> 4) << 3);
      const float* src = wv + ((size_t)((mg << 4) + r) * T_ + tt) * D_ + d;
      float4 xa = *(const float4*)src;
      float4 xb = *(const float4*)(src + 4);
      bf16x8 v;
      v[0] = (__bf16)xa.x; v[1] = (__bf16)xa.y; v[2] = (__bf16)xa.z; v[3] = (__bf16)xa.w;
      v[4] = (__bf16)xb.x; v[5] = (__bf16)xb.y; v[6] = (__bf16)xb.z; v[7] = (__bf16)xb.w;
      *(bf16x8*)&xlds[buf][(ktx << 9) + (le << 3)] = v;
    }
  };

  auto xpart = [&](int buf) {
    f32x4 a = {0.f, 0.f, 0.f, 0.f};
#pragma unroll
    for (int kt = 0; kt < 16; ++kt) {
      bf16x8 af = *(const bf16x8*)&xlds[buf][(kt << 9) + (lane << 3)];
      a = __builtin_amdgcn_mfma_f32_16x16x32_bf16(
          af, __builtin_bit_cast(bf16x8, wfrag[kt]), a, 0, 0, 0);
    }
    return a;
  };

  // ---- prologue ----
  load_x(0, 0);
  __syncthreads();
  f32x4 acc = xpart(0);
  load_x(1, 1);
  publish_h(hg0);
  __syncthreads();   // drains vmcnt: h[0] sc1 stores acked at LLC
  arrive(1);
  wait_stage(1, hg0);
  __syncthreads();

  for (int t = 0; t < T_; ++t) {
    const int par = t & 1;
    unsigned int* hdst = par ? hg0 : hg1;  // h[t+1] parity

    // ---- phase A (critical path): h-MFMAs (2 chains), gates, publish ----
    f32x4 acc2 = {0.f, 0.f, 0.f, 0.f};
#pragma unroll
    for (int kt = 0; kt < 8; ++kt) {
      bf16x8 a0 = *(const bf16x8*)&hlds[((2 * kt) << 9) + (lane << 3)];
      bf16x8 a1 = *(const bf16x8*)&hlds[((2 * kt + 1) << 9) + (lane << 3)];
      acc = __builtin_amdgcn_mfma_f32_16x16x32_bf16(
          a0, __builtin_bit_cast(bf16x8, wfrag[16 + 2 * kt]), acc, 0, 0, 0);
      acc2 = __builtin_amdgcn_mfma_f32_16x16x32_bf16(
          a1, __builtin_bit_cast(bf16x8, wfrag[17 + 2 * kt]), acc2, 0, 0, 0);
    }
    {  // C/D layout: col=lane&15, row=(lane>>4)*4+reg
      int q = lane >> 4, cl = lane & 15;
#pragma unroll
      for (int v = 0; v < 4; ++v)
        zbuf[w][q * 4 + v][cl] = acc[v] + acc2[v] + bv;
    }
    __syncthreads();
    {
      int ej = ec >> 4, ecl = ec & 15;
      float zi = zbuf[ej * 4 + 0][er][ecl];
      float zj = zbuf[ej * 4 + 1][er][ecl];
      float zf = zbuf[ej * 4 + 2][er][ecl];
      float zo = zbuf[ej * 4 + 3][er][ecl];
      float si = fast_sigmoid(zi);
      float sf = fast_sigmoid(zf + 1.f);  // FORGET_BIAS
      float so = fast_sigmoid(zo);
      float tj = fast_tanh(zj);
      float nc = c_reg * sf + si * tj;
      float nh = fast_tanh(nc) * so;
      bool m = t < nwv;
      c_reg = m ? nc : c_reg;
      h_reg = m ? nh : h_reg;
      publish_h(hdst);
      out[(size_t)t * (B_ * H_) + grow * H_ + gcol] = m ? nh : 0.f;
    }
    __syncthreads();   // h[t+1] sc1 stores acked before flag
    arrive(t + 2);
    // ---- phase B (overlap): x-part of t+1, prefetch x[t+2], then stage ----
    if (t + 1 < T_) {
      acc = xpart(1 - par);   // x[t+1], staged at t-1
      load_x(par, t + 2);     // refill buffer last read at t-1
      wait_stage(t + 2, hdst);  // stage h[t+1] into hlds
    }
    __syncthreads();
  }

  size_t base = (size_t)T_ * (B_ * H_);
  out[base + grow * H_ + gcol] = c_reg;
  out[base + B_ * H_ + grow * H_ + gcol] = h_reg;
}

extern "C" void kernel_launch(void* const* d_in, const int* in_sizes, int n_in,
                              void* d_out, int out_size, void* d_ws, size_t ws_size,
                              hipStream_t stream) {
  const float* wv = (const float*)d_in[0];    // [B,T,D]
  const int* nw = (const int*)d_in[1];        // [B]
  const float* ic = (const float*)d_in[2];    // [B,H]
  const float* ih = (const float*)d_in[3];    // [B,H]
  const float* W = (const float*)d_in[4];     // [D+H, 4H]
  const float* bias = (const float*)d_in[5];  // [4H]
  float* out = (float*)d_out;

  char* ws = (char*)d_ws;
  unsigned short* Wp = (unsigned short*)ws;                // 4 MB packed W
  unsigned int* hg = (unsigned int*)(ws + (4u << 20));     // 256 KB h ping-pong
  int* bar = (int*)(ws + (4u << 20) + (256u << 10));       // 8 KB epoch flags

  init_bar_kernel<<<8, 256, 0, stream>>>(bar);
  pack_w_kernel<<<(1 << 21) / 256, 256, 0, stream>>>(W, Wp);
  lstm_persistent<<<128, 512, 0, stream>>>(wv, nw, ic, ih, bias, Wp, hg, bar, out);
}